// Round 2
// baseline (437.973 us; speedup 1.0000x reference)
//
#include <hip/hip_runtime.h>
#include <stdint.h>

typedef __bf16 bf16x8 __attribute__((ext_vector_type(8)));
typedef float  floatx4 __attribute__((ext_vector_type(4)));
typedef int    i32x4  __attribute__((ext_vector_type(4)));

#define T_LEN 512
#define BT    4       // batch rows per block -> 128 blocks; rows at tile rows {0,4,8,12}
#define NTHR  512     // 8 waves; waves 0-3 = layer0 (+x staging), waves 4-7 = layer1
#define XS    72      // xb row stride (bf16)
#define HIS   144     // h int8 LDS row stride (bytes)
#define HFS   132     // final h1 fp32 row stride

#if __has_builtin(__builtin_amdgcn_exp2f)
#define EXP2(x) __builtin_amdgcn_exp2f(x)
#else
#define EXP2(x) exp2f(x)
#endif

#define MFMA_BF(a,b,c)  __builtin_amdgcn_mfma_f32_16x16x32_bf16((a),(b),(c),0,0,0)
#define MFMA_I8(a,b,c)  __builtin_amdgcn_mfma_i32_16x16x64_i8((a),(b),(c),0,0,0)

// Raw workgroup barrier: drains LDS ops only (lgkmcnt), NOT vmcnt — global
// x-prefetch loads stay in flight across barriers (T4: never vmcnt(0) in the
// main loop). "memory" clobber pins all compiler-visible memory ops on their
// side of the barrier; compiler still emits counted vmcnt before vx use.
#define BARRIER_LDS() asm volatile("s_waitcnt lgkmcnt(0)\n\ts_barrier" ::: "memory")

// quantization: h -> q*1/127 ; w -> q*1/254 (|w| clamped at 0.5)
#define L2E   1.4426950408889634f
#define S_RZ  (-L2E / (254.f * 127.f))        // i32 -> -log2e * preact
#define S_N   (-2.f * L2E / (254.f * 127.f))  // i32 -> -2*log2e * preact

__device__ __forceinline__ float rcpf(float x) { return __builtin_amdgcn_rcpf(x); }

// bf16 B-fragment with folded scale (x-side weights)
__device__ __forceinline__ bf16x8 wfrag_bf(const float* W, int ldk, int row, int k0, float scale) {
    const float* p = W + (size_t)row * ldk + k0;
    bf16x8 r;
    #pragma unroll
    for (int j = 0; j < 8; ++j) r[j] = (__bf16)(p[j] * scale);
    return r;
}
// int8 B-fragment: 16 weights along K, quantized *254, clamped +-127, packed LE
__device__ __forceinline__ i32x4 wfrag_i8(const float* W, int ldk, int row, int k0) {
    const float* p = W + (size_t)row * ldk + k0;
    i32x4 r;
    #pragma unroll
    for (int d = 0; d < 4; ++d) {
        uint32_t dw = 0;
        #pragma unroll
        for (int j = 0; j < 4; ++j) {
            float q = __builtin_rintf(p[d * 4 + j] * 254.f);
            q = fminf(127.f, fmaxf(-127.f, q));
            dw |= ((uint32_t)((int)q & 0xff)) << (8 * j);
        }
        r[d] = (int)dw;
    }
    return r;
}

// Schedule: pre/post phase split around ONE raw (lgkm-only) barrier per step.
//   L0 (lag 0):  pre = x-side bf16; post = hidden i8.
//   L1 (lag 2):  pre = input-side i8 on h0; post = hidden i8 on h1.
// x prefetch is 2-deep in registers (each load ~2 intervals in flight) and is
// NOT drained at barriers. All cross-wave LDS deps: write -> lgkmcnt(0)-drained
// barrier -> read. Math identical to previous rounds -> bit-identical output.
__global__ __launch_bounds__(NTHR, 2) void gru_fused(
    const float* __restrict__ x,
    const float* __restrict__ Wih0, const float* __restrict__ Whh0,
    const float* __restrict__ bih0, const float* __restrict__ bhh0,
    const float* __restrict__ Wih1, const float* __restrict__ Whh1,
    const float* __restrict__ bih1, const float* __restrict__ bhh1,
    const float* __restrict__ Wfc,  const float* __restrict__ bfc,
    float* __restrict__ out)
{
    __shared__ __align__(16) __bf16      xb[2][16 * XS];
    __shared__ __align__(16) signed char h0i[2][16 * HIS];
    __shared__ __align__(16) signed char h1i[2][16 * HIS];
    __shared__ __align__(16) float       hfin[16 * HFS];

    const int tid  = threadIdx.x;
    const int lane = tid & 63;
    const int ln16 = lane & 15;
    const int quad = lane >> 4;
    const int q8   = quad * 8;        // bf16 k-offset (elements)
    const int q16  = quad * 16;       // int8 k-offset (bytes)
    const int wave = tid >> 6;        // 0..7
    const int wv   = wave & 3;
    const int brow = blockIdx.x * BT;

    for (int i = tid; i < 16 * HIS; i += NTHR) {
        h0i[0][i] = 0; h0i[1][i] = 0;
        h1i[0][i] = 0; h1i[1][i] = 0;
    }
    for (int i = tid; i < 16 * XS; i += NTHR) {   // dead x rows stay zero
        xb[0][i] = (__bf16)0.f; xb[1][i] = (__bf16)0.f;
    }
    __syncthreads();                  // init barrier (removes init/stage race)

    float hf[2] = {0.f, 0.f};

    if (wave < 4) {
        // ===== layer-0: cols [32wv,32wv+32); x-side bf16, hidden int8 =====
        float bNi[2], bNh[2], bR[2], bZ[2];
        bf16x8 wI[2][3][2];           // x-side, scale-folded (12 frags)
        i32x4  wH[2][3][2];           // hidden int8 K=64 (12 frags)
        #pragma unroll
        for (int t2 = 0; t2 < 2; ++t2) {
            const int c = wv * 32 + t2 * 16 + ln16;
            bNi[t2] = -2.f * L2E * bih0[256 + c];
            bNh[t2] = -2.f * L2E * bhh0[256 + c];
            bR[t2]  = -L2E * (bih0[c] + bhh0[c]);
            bZ[t2]  = -L2E * (bih0[128 + c] + bhh0[128 + c]);
            #pragma unroll
            for (int g = 0; g < 3; ++g) {
                const int row = g * 128 + c;
                const float sc = (g == 2) ? (-2.f * L2E) : (-L2E);
                #pragma unroll
                for (int q = 0; q < 2; ++q) {
                    wI[t2][g][q] = wfrag_bf(Wih0, 64, row, q * 32 + q8, sc);
                    wH[t2][g][q] = wfrag_i8(Whh0, 128, row, q * 64 + q16);
                }
            }
        }

        // staging: threads 0..255, batch row tid>>6, col tid&63
        const int sb = tid >> 6, scg = tid & 63;
        const float* xp = x + (size_t)(brow + sb) * T_LEN * 64 + scg;
        // prologue: x(0)->xb[0], x(1)->xb[1]; prefetch x(2), x(3) (2-deep)
        xb[0][(sb * 4) * XS + scg] = (__bf16)xp[0];
        xb[1][(sb * 4) * XS + scg] = (__bf16)xp[64];
        float vxA = xp[2 * 64];
        float vxB = xp[3 * 64];
        __syncthreads();              // publish xb[0], xb[1] among L0 waves

        floatx4 pF[2][3];             // pre-issued x-side acc (R, Z, Ni)
        {   // pre-issue x-side for step 0 (drains under loop-top barrier)
            bf16x8 ax0 = *(const bf16x8*)&xb[0][ln16 * XS + q8];
            bf16x8 ax1 = *(const bf16x8*)&xb[0][ln16 * XS + 32 + q8];
            #pragma unroll
            for (int t2 = 0; t2 < 2; ++t2) {
                floatx4 fR  = {bR[t2],  bR[t2],  bR[t2],  bR[t2]};
                floatx4 fZ  = {bZ[t2],  bZ[t2],  bZ[t2],  bZ[t2]};
                floatx4 fNi = {bNi[t2], bNi[t2], bNi[t2], bNi[t2]};
                fR  = MFMA_BF(ax0, wI[t2][0][0], fR);  fR  = MFMA_BF(ax1, wI[t2][0][1], fR);
                fZ  = MFMA_BF(ax0, wI[t2][1][0], fZ);  fZ  = MFMA_BF(ax1, wI[t2][1][1], fZ);
                fNi = MFMA_BF(ax0, wI[t2][2][0], fNi); fNi = MFMA_BF(ax1, wI[t2][2][1], fNi);
                pF[t2][0] = fR; pF[t2][1] = fZ; pF[t2][2] = fNi;
            }
        }

        for (int tt = 0; tt <= T_LEN + 1; ++tt) {
            __builtin_amdgcn_sched_barrier(0);   // pin pre-phase before barrier
            BARRIER_LDS();            // the ONLY per-iter barrier (lgkm only)
            // early staging: write x(tt+2) into xb[tt&1]; issue load x(tt+4)
            // (xb[tt&1]'s last reader drained at this barrier -> WAR-safe)
            xb[tt & 1][(sb * 4) * XS + scg] = (__bf16)vxA;
            vxA = vxB;
            {
                int tl = tt + 4; if (tl > T_LEN - 1) tl = T_LEN - 1;
                vxB = xp[(size_t)tl * 64];
            }

            if (tt < T_LEN) {         // post-phase: hidden side of step tt
                const int Rp = (tt + 1) & 1, Wc = tt & 1;   // read h0(tt-1), write h0(tt)
                i32x4 ah[2];
                #pragma unroll
                for (int q = 0; q < 2; ++q)
                    ah[q] = *(const i32x4*)&h0i[Rp][ln16 * HIS + q * 64 + q16];
                #pragma unroll
                for (int t2 = 0; t2 < 2; ++t2) {
                    i32x4 cR = {0,0,0,0}, cZ = {0,0,0,0}, cNh = {0,0,0,0};
                    #pragma unroll
                    for (int q = 0; q < 2; ++q) {
                        cR  = MFMA_I8(ah[q], wH[t2][0][q], cR);
                        cZ  = MFMA_I8(ah[q], wH[t2][1][q], cZ);
                        cNh = MFMA_I8(ah[q], wH[t2][2][q], cNh);
                    }
                    // gate math (tile row quad*4 = acc[0]); scales pre-folded
                    const float pr  = fmaf((float)cR[0],  S_RZ, pF[t2][0][0]);
                    const float pz  = fmaf((float)cZ[0],  S_RZ, pF[t2][1][0]);
                    const float phn = fmaf((float)cNh[0], S_N,  bNh[t2]);
                    const float r = rcpf(1.f + EXP2(pr));
                    const float z = rcpf(1.f + EXP2(pz));
                    const float n = 2.f * rcpf(1.f + EXP2(fmaf(r, phn, pF[t2][2][0]))) - 1.f;
                    const float h = n + z * (hf[t2] - n);
                    hf[t2] = h;
                    const int cc = wv * 32 + t2 * 16 + ln16;
                    h0i[Wc][(quad * 4) * HIS + cc] =
                        (signed char)(int)__builtin_rintf(h * 127.f);
                }
            }

            if (tt + 1 < T_LEN) {     // pre-phase: x-side of step tt+1
                const int Rn = (tt + 1) & 1;
                bf16x8 ax0 = *(const bf16x8*)&xb[Rn][ln16 * XS + q8];
                bf16x8 ax1 = *(const bf16x8*)&xb[Rn][ln16 * XS + 32 + q8];
                #pragma unroll
                for (int t2 = 0; t2 < 2; ++t2) {
                    floatx4 fR  = {bR[t2],  bR[t2],  bR[t2],  bR[t2]};
                    floatx4 fZ  = {bZ[t2],  bZ[t2],  bZ[t2],  bZ[t2]};
                    floatx4 fNi = {bNi[t2], bNi[t2], bNi[t2], bNi[t2]};
                    fR  = MFMA_BF(ax0, wI[t2][0][0], fR);  fR  = MFMA_BF(ax1, wI[t2][0][1], fR);
                    fZ  = MFMA_BF(ax0, wI[t2][1][0], fZ);  fZ  = MFMA_BF(ax1, wI[t2][1][1], fZ);
                    fNi = MFMA_BF(ax0, wI[t2][2][0], fNi); fNi = MFMA_BF(ax1, wI[t2][2][1], fNi);
                    pF[t2][0] = fR; pF[t2][1] = fZ; pF[t2][2] = fNi;
                }
            }
        }
    } else {
        // ===== layer-1 (lag 2): cols [32wv,32wv+32); all int8 =====
        float bNi1[2], bNh1[2], bR1[2], bZ1[2];
        i32x4 wI[2][3][2], wH[2][3][2];   // 24 frags = 96 VGPRs
        #pragma unroll
        for (int t2 = 0; t2 < 2; ++t2) {
            const int c = wv * 32 + t2 * 16 + ln16;
            bNi1[t2] = -2.f * L2E * bih1[256 + c];
            bNh1[t2] = -2.f * L2E * bhh1[256 + c];
            bR1[t2]  = -L2E * (bih1[c] + bhh1[c]);
            bZ1[t2]  = -L2E * (bih1[128 + c] + bhh1[128 + c]);
            #pragma unroll
            for (int g = 0; g < 3; ++g) {
                const int row = g * 128 + c;
                #pragma unroll
                for (int q = 0; q < 2; ++q) {
                    wI[t2][g][q] = wfrag_i8(Wih1, 128, row, q * 64 + q16);
                    wH[t2][g][q] = wfrag_i8(Whh1, 128, row, q * 64 + q16);
                }
            }
        }
        __syncthreads();              // match L0's xb-publish barrier

        i32x4 pI[2][3];               // pre-issued input-side acc (R, Z, Ni)
        for (int tt = 0; tt <= T_LEN + 1; ++tt) {
            __builtin_amdgcn_sched_barrier(0);
            BARRIER_LDS();
            if (tt >= 2) {            // post-phase: step s = tt-2
                const int Rp = (tt + 1) & 1;   // h1(tt-3) in buf (tt-3)&1
                const int Wc = tt & 1;         // h1(tt-2) -> buf (tt-2)&1
                i32x4 a1[2];
                #pragma unroll
                for (int q = 0; q < 2; ++q)
                    a1[q] = *(const i32x4*)&h1i[Rp][ln16 * HIS + q * 64 + q16];
                #pragma unroll
                for (int t2 = 0; t2 < 2; ++t2) {
                    i32x4 cR = pI[t2][0], cZ = pI[t2][1], cNh = {0,0,0,0};
                    #pragma unroll
                    for (int q = 0; q < 2; ++q) {     // hidden side (h1), same scale
                        cR  = MFMA_I8(a1[q], wH[t2][0][q], cR);
                        cZ  = MFMA_I8(a1[q], wH[t2][1][q], cZ);
                        cNh = MFMA_I8(a1[q], wH[t2][2][q], cNh);
                    }
                    const float pr  = fmaf((float)cR[0],       S_RZ, bR1[t2]);
                    const float pz  = fmaf((float)cZ[0],       S_RZ, bZ1[t2]);
                    const float pin = fmaf((float)pI[t2][2][0], S_N, bNi1[t2]);
                    const float phn = fmaf((float)cNh[0],      S_N,  bNh1[t2]);
                    const float r = rcpf(1.f + EXP2(pr));
                    const float z = rcpf(1.f + EXP2(pz));
                    const float n = 2.f * rcpf(1.f + EXP2(fmaf(r, phn, pin))) - 1.f;
                    const float h = n + z * (hf[t2] - n);
                    hf[t2] = h;
                    const int cc = wv * 32 + t2 * 16 + ln16;
                    h1i[Wc][(quad * 4) * HIS + cc] =
                        (signed char)(int)__builtin_rintf(h * 127.f);
                }
            }
            if (tt >= 1 && tt <= T_LEN) {   // pre-phase: input side for step tt-1
                const int Rh = (tt + 1) & 1;     // h0(tt-1), published THIS barrier
                i32x4 ah[2];
                #pragma unroll
                for (int q = 0; q < 2; ++q)
                    ah[q] = *(const i32x4*)&h0i[Rh][ln16 * HIS + q * 64 + q16];
                #pragma unroll
                for (int t2 = 0; t2 < 2; ++t2) {
                    i32x4 cR = {0,0,0,0}, cZ = {0,0,0,0}, cNi = {0,0,0,0};
                    #pragma unroll
                    for (int q = 0; q < 2; ++q) {
                        cR  = MFMA_I8(ah[q], wI[t2][0][q], cR);
                        cZ  = MFMA_I8(ah[q], wI[t2][1][q], cZ);
                        cNi = MFMA_I8(ah[q], wI[t2][2][q], cNi);
                    }
                    pI[t2][0] = cR; pI[t2][1] = cZ; pI[t2][2] = cNi;
                }
            }
        }
        // publish final h1 (fp32 state, not quantized) for the FC epilogue
        #pragma unroll
        for (int t2 = 0; t2 < 2; ++t2)
            hfin[(quad * 4) * HFS + wv * 32 + t2 * 16 + ln16] = hf[t2];
    }

    __syncthreads();
    // final FC: out[b] = h1(T-1)[b,:] . Wfc + bfc  (tile rows 0,4,8,12)
    {
        const int row = tid >> 5, l = tid & 31;
        if ((row & 3) == 0) {
            float s = 0.f;
            #pragma unroll
            for (int k = 0; k < 4; ++k)
                s += hfin[row * HFS + l + 32 * k] * Wfc[l + 32 * k];
            #pragma unroll
            for (int d = 16; d >= 1; d >>= 1) s += __shfl_down(s, d, 32);
            if (l == 0) out[brow + (row >> 2)] = s + bfc[0];
        }
    }
}

extern "C" void kernel_launch(void* const* d_in, const int* in_sizes, int n_in,
                              void* d_out, int out_size, void* d_ws, size_t ws_size,
                              hipStream_t stream) {
    const float* x    = (const float*)d_in[0];
    const float* Wih0 = (const float*)d_in[1];
    const float* Whh0 = (const float*)d_in[2];
    const float* bih0 = (const float*)d_in[3];
    const float* bhh0 = (const float*)d_in[4];
    const float* Wih1 = (const float*)d_in[5];
    const float* Whh1 = (const float*)d_in[6];
    const float* bih1 = (const float*)d_in[7];
    const float* bhh1 = (const float*)d_in[8];
    const float* Wfc  = (const float*)d_in[9];
    const float* bfc  = (const float*)d_in[10];
    float* out = (float*)d_out;

    hipLaunchKernelGGL(gru_fused, dim3(512 / BT), dim3(NTHR), 0, stream,
                       x, Wih0, Whh0, bih0, bhh0, Wih1, Whh1, bih1, bhh1, Wfc, bfc, out);
}

// Round 3
// 418.688 us; speedup vs baseline: 1.0461x; 1.0461x over previous
//
#include <hip/hip_runtime.h>
#include <stdint.h>

typedef __bf16 bf16x8 __attribute__((ext_vector_type(8)));
typedef float  floatx4 __attribute__((ext_vector_type(4)));
typedef int    i32x4  __attribute__((ext_vector_type(4)));

#define T_LEN 512
#define BT    4       // batch rows per block -> 128 blocks; rows at tile rows {0,4,8,12}
#define NTHR  1024    // 16 waves; waves 0-7 = layer0 (cols 16w..16w+16, + x staging),
                      //           waves 8-15 = layer1. 4 waves/SIMD for TLP.
#define XS    72      // xb row stride (bf16)
#define HIS   144     // h int8 LDS row stride (bytes)
#define HFS   132     // final h1 fp32 row stride

#if __has_builtin(__builtin_amdgcn_exp2f)
#define EXP2(x) __builtin_amdgcn_exp2f(x)
#else
#define EXP2(x) exp2f(x)
#endif

#define MFMA_BF(a,b,c)  __builtin_amdgcn_mfma_f32_16x16x32_bf16((a),(b),(c),0,0,0)
#define MFMA_I8(a,b,c)  __builtin_amdgcn_mfma_i32_16x16x64_i8((a),(b),(c),0,0,0)

// Raw workgroup barrier: drains LDS ops only (lgkmcnt), NOT vmcnt — global
// x-prefetch loads stay in flight across barriers.
#define BARRIER_LDS() asm volatile("s_waitcnt lgkmcnt(0)\n\ts_barrier" ::: "memory")

// quantization: h -> q*1/127 ; w -> q*1/254 (|w| clamped at 0.5)
#define L2E   1.4426950408889634f
#define S_RZ  (-L2E / (254.f * 127.f))        // i32 -> -log2e * preact
#define S_N   (-2.f * L2E / (254.f * 127.f))  // i32 -> -2*log2e * preact

__device__ __forceinline__ float rcpf(float x) { return __builtin_amdgcn_rcpf(x); }

// bf16 B-fragment with folded scale (x-side weights)
__device__ __forceinline__ bf16x8 wfrag_bf(const float* W, int ldk, int row, int k0, float scale) {
    const float* p = W + (size_t)row * ldk + k0;
    bf16x8 r;
    #pragma unroll
    for (int j = 0; j < 8; ++j) r[j] = (__bf16)(p[j] * scale);
    return r;
}
// int8 B-fragment: 16 weights along K, quantized *254, clamped +-127, packed LE
__device__ __forceinline__ i32x4 wfrag_i8(const float* W, int ldk, int row, int k0) {
    const float* p = W + (size_t)row * ldk + k0;
    i32x4 r;
    #pragma unroll
    for (int d = 0; d < 4; ++d) {
        uint32_t dw = 0;
        #pragma unroll
        for (int j = 0; j < 4; ++j) {
            float q = __builtin_rintf(p[d * 4 + j] * 254.f);
            q = fminf(127.f, fmaxf(-127.f, q));
            dw |= ((uint32_t)((int)q & 0xff)) << (8 * j);
        }
        r[d] = (int)dw;
    }
    return r;
}

// 16-wave version: same total per-block work, split 2x finer (16 cols/wave)
// so each SIMD holds 4 waves (2 L0 + 2 L1) -> stall windows of one wave
// (ds_read latency, gate VALU/trans chains) overlap other waves' MFMAs.
// Per-column math identical to the 8-wave version -> bit-identical output.
//   L0 (lag 0):  pre = x-side bf16; post = hidden i8.
//   L1 (lag 2):  pre = input-side i8 on h0; post = hidden i8 on h1.
// ONE lgkm-only barrier per step; x prefetch 2-deep in registers, never
// drained at barriers. h0(t) in h0i[t&1]; h1(s) in h1i[s&1]; x(t) in xb[t&1].
__global__ __launch_bounds__(NTHR, 4) void gru_fused(
    const float* __restrict__ x,
    const float* __restrict__ Wih0, const float* __restrict__ Whh0,
    const float* __restrict__ bih0, const float* __restrict__ bhh0,
    const float* __restrict__ Wih1, const float* __restrict__ Whh1,
    const float* __restrict__ bih1, const float* __restrict__ bhh1,
    const float* __restrict__ Wfc,  const float* __restrict__ bfc,
    float* __restrict__ out)
{
    __shared__ __align__(16) __bf16      xb[2][16 * XS];
    __shared__ __align__(16) signed char h0i[2][16 * HIS];
    __shared__ __align__(16) signed char h1i[2][16 * HIS];
    __shared__ __align__(16) float       hfin[16 * HFS];

    const int tid  = threadIdx.x;
    const int lane = tid & 63;
    const int ln16 = lane & 15;
    const int quad = lane >> 4;
    const int q8   = quad * 8;        // bf16 k-offset (elements)
    const int q16  = quad * 16;       // int8 k-offset (bytes)
    const int wave = tid >> 6;        // 0..15
    const int brow = blockIdx.x * BT;

    for (int i = tid; i < 16 * HIS; i += NTHR) {
        h0i[0][i] = 0; h0i[1][i] = 0;
        h1i[0][i] = 0; h1i[1][i] = 0;
    }
    for (int i = tid; i < 16 * XS; i += NTHR) {   // dead x rows stay zero
        xb[0][i] = (__bf16)0.f; xb[1][i] = (__bf16)0.f;
    }
    __syncthreads();                  // init barrier (removes init/stage race)

    if (wave < 8) {
        // ===== layer-0: cols [16w,16w+16); x-side bf16, hidden int8 =====
        const int wv = wave;
        const int c  = wv * 16 + ln16;
        const float bNi = -2.f * L2E * bih0[256 + c];
        const float bNh = -2.f * L2E * bhh0[256 + c];
        const float bR  = -L2E * (bih0[c] + bhh0[c]);
        const float bZ  = -L2E * (bih0[128 + c] + bhh0[128 + c]);
        bf16x8 wI[3][2];              // x-side, scale-folded (6 frags)
        i32x4  wH[3][2];              // hidden int8 K=64 (6 frags)
        #pragma unroll
        for (int g = 0; g < 3; ++g) {
            const int row = g * 128 + c;
            const float sc = (g == 2) ? (-2.f * L2E) : (-L2E);
            #pragma unroll
            for (int q = 0; q < 2; ++q) {
                wI[g][q] = wfrag_bf(Wih0, 64, row, q * 32 + q8, sc);
                wH[g][q] = wfrag_i8(Whh0, 128, row, q * 64 + q16);
            }
        }

        // staging: 256 loaders spread across all 8 L0 waves (lanes 0..31):
        // loader index = wv*32+lane -> batch row idx>>6, col idx&63
        const bool loader = (lane < 32);
        const int lidx = wv * 32 + lane;
        const int sb = (lidx >> 6) & 3, scg = lidx & 63;
        const float* xp = x + (size_t)(brow + sb) * T_LEN * 64 + scg;
        float vxA = 0.f, vxB = 0.f;
        if (loader) {
            // prologue: x(0)->xb[0], x(1)->xb[1]; prefetch x(2), x(3)
            xb[0][(sb * 4) * XS + scg] = (__bf16)xp[0];
            xb[1][(sb * 4) * XS + scg] = (__bf16)xp[64];
            vxA = xp[2 * 64];
            vxB = xp[3 * 64];
        }
        __syncthreads();              // publish xb[0], xb[1]

        float hfv = 0.f;
        floatx4 pR, pZ, pNi;          // pre-issued x-side accumulators
        {   // pre-issue x-side for step 0 (drains under loop-top barrier)
            bf16x8 ax0 = *(const bf16x8*)&xb[0][ln16 * XS + q8];
            bf16x8 ax1 = *(const bf16x8*)&xb[0][ln16 * XS + 32 + q8];
            floatx4 fR  = {bR, bR, bR, bR};
            floatx4 fZ  = {bZ, bZ, bZ, bZ};
            floatx4 fNi = {bNi, bNi, bNi, bNi};
            fR  = MFMA_BF(ax0, wI[0][0], fR);  fR  = MFMA_BF(ax1, wI[0][1], fR);
            fZ  = MFMA_BF(ax0, wI[1][0], fZ);  fZ  = MFMA_BF(ax1, wI[1][1], fZ);
            fNi = MFMA_BF(ax0, wI[2][0], fNi); fNi = MFMA_BF(ax1, wI[2][1], fNi);
            pR = fR; pZ = fZ; pNi = fNi;
        }

        for (int tt = 0; tt <= T_LEN + 1; ++tt) {
            __builtin_amdgcn_sched_barrier(0);   // pin pre-phase before barrier
            BARRIER_LDS();            // the ONLY per-iter barrier (lgkm only)
            // early staging: write x(tt+2) into xb[tt&1]; issue load x(tt+4)
            if (loader) {
                xb[tt & 1][(sb * 4) * XS + scg] = (__bf16)vxA;
                vxA = vxB;
                int tl = tt + 4; if (tl > T_LEN - 1) tl = T_LEN - 1;
                vxB = xp[(size_t)tl * 64];
            }

            if (tt < T_LEN) {         // post-phase: hidden side of step tt
                const int Rp = (tt + 1) & 1, Wc = tt & 1;
                i32x4 ah[2];
                #pragma unroll
                for (int q = 0; q < 2; ++q)
                    ah[q] = *(const i32x4*)&h0i[Rp][ln16 * HIS + q * 64 + q16];
                i32x4 cR = {0,0,0,0}, cZ = {0,0,0,0}, cNh = {0,0,0,0};
                #pragma unroll
                for (int q = 0; q < 2; ++q) {
                    cR  = MFMA_I8(ah[q], wH[0][q], cR);
                    cZ  = MFMA_I8(ah[q], wH[1][q], cZ);
                    cNh = MFMA_I8(ah[q], wH[2][q], cNh);
                }
                // gate math (tile row quad*4 = acc[0]); scales pre-folded
                const float pr  = fmaf((float)cR[0],  S_RZ, pR[0]);
                const float pz  = fmaf((float)cZ[0],  S_RZ, pZ[0]);
                const float phn = fmaf((float)cNh[0], S_N,  bNh);
                const float r = rcpf(1.f + EXP2(pr));
                const float z = rcpf(1.f + EXP2(pz));
                const float n = 2.f * rcpf(1.f + EXP2(fmaf(r, phn, pNi[0]))) - 1.f;
                const float h = n + z * (hfv - n);
                hfv = h;
                h0i[Wc][(quad * 4) * HIS + c] =
                    (signed char)(int)__builtin_rintf(h * 127.f);
            }

            if (tt + 1 < T_LEN) {     // pre-phase: x-side of step tt+1
                const int Rn = (tt + 1) & 1;
                bf16x8 ax0 = *(const bf16x8*)&xb[Rn][ln16 * XS + q8];
                bf16x8 ax1 = *(const bf16x8*)&xb[Rn][ln16 * XS + 32 + q8];
                floatx4 fR  = {bR, bR, bR, bR};
                floatx4 fZ  = {bZ, bZ, bZ, bZ};
                floatx4 fNi = {bNi, bNi, bNi, bNi};
                fR  = MFMA_BF(ax0, wI[0][0], fR);  fR  = MFMA_BF(ax1, wI[0][1], fR);
                fZ  = MFMA_BF(ax0, wI[1][0], fZ);  fZ  = MFMA_BF(ax1, wI[1][1], fZ);
                fNi = MFMA_BF(ax0, wI[2][0], fNi); fNi = MFMA_BF(ax1, wI[2][1], fNi);
                pR = fR; pZ = fZ; pNi = fNi;
            }
        }
    } else {
        // ===== layer-1 (lag 2): cols [16wv,16wv+16); all int8 =====
        const int wv = wave - 8;
        const int c  = wv * 16 + ln16;
        const float bNi1 = -2.f * L2E * bih1[256 + c];
        const float bNh1 = -2.f * L2E * bhh1[256 + c];
        const float bR1  = -L2E * (bih1[c] + bhh1[c]);
        const float bZ1  = -L2E * (bih1[128 + c] + bhh1[128 + c]);
        i32x4 wI[3][2], wH[3][2];     // 12 frags = 48 VGPRs
        #pragma unroll
        for (int g = 0; g < 3; ++g) {
            const int row = g * 128 + c;
            #pragma unroll
            for (int q = 0; q < 2; ++q) {
                wI[g][q] = wfrag_i8(Wih1, 128, row, q * 64 + q16);
                wH[g][q] = wfrag_i8(Whh1, 128, row, q * 64 + q16);
            }
        }
        __syncthreads();              // match L0's xb-publish barrier

        float hfv = 0.f;
        i32x4 pIR, pIZ, pINi;         // pre-issued input-side accumulators
        for (int tt = 0; tt <= T_LEN + 1; ++tt) {
            __builtin_amdgcn_sched_barrier(0);
            BARRIER_LDS();
            if (tt >= 2) {            // post-phase: step s = tt-2
                const int Rp = (tt + 1) & 1;   // h1(tt-3) in buf (tt-3)&1
                const int Wc = tt & 1;         // h1(tt-2) -> buf (tt-2)&1
                i32x4 a1[2];
                #pragma unroll
                for (int q = 0; q < 2; ++q)
                    a1[q] = *(const i32x4*)&h1i[Rp][ln16 * HIS + q * 64 + q16];
                i32x4 cR = pIR, cZ = pIZ, cNh = {0,0,0,0};
                #pragma unroll
                for (int q = 0; q < 2; ++q) {     // hidden side (h1), same scale
                    cR  = MFMA_I8(a1[q], wH[0][q], cR);
                    cZ  = MFMA_I8(a1[q], wH[1][q], cZ);
                    cNh = MFMA_I8(a1[q], wH[2][q], cNh);
                }
                const float pr  = fmaf((float)cR[0],    S_RZ, bR1);
                const float pz  = fmaf((float)cZ[0],    S_RZ, bZ1);
                const float pin = fmaf((float)pINi[0],  S_N,  bNi1);
                const float phn = fmaf((float)cNh[0],   S_N,  bNh1);
                const float r = rcpf(1.f + EXP2(pr));
                const float z = rcpf(1.f + EXP2(pz));
                const float n = 2.f * rcpf(1.f + EXP2(fmaf(r, phn, pin))) - 1.f;
                const float h = n + z * (hfv - n);
                hfv = h;
                h1i[Wc][(quad * 4) * HIS + c] =
                    (signed char)(int)__builtin_rintf(h * 127.f);
            }
            if (tt >= 1 && tt <= T_LEN) {   // pre-phase: input side for step tt-1
                const int Rh = (tt + 1) & 1;     // h0(tt-1), published THIS barrier
                i32x4 ah[2];
                #pragma unroll
                for (int q = 0; q < 2; ++q)
                    ah[q] = *(const i32x4*)&h0i[Rh][ln16 * HIS + q * 64 + q16];
                i32x4 cR = {0,0,0,0}, cZ = {0,0,0,0}, cNi = {0,0,0,0};
                #pragma unroll
                for (int q = 0; q < 2; ++q) {
                    cR  = MFMA_I8(ah[q], wI[0][q], cR);
                    cZ  = MFMA_I8(ah[q], wI[1][q], cZ);
                    cNi = MFMA_I8(ah[q], wI[2][q], cNi);
                }
                pIR = cR; pIZ = cZ; pINi = cNi;
            }
        }
        // publish final h1 (fp32 state, not quantized) for the FC epilogue
        hfin[(quad * 4) * HFS + c] = hfv;
    }

    __syncthreads();
    // final FC: out[b] = h1(T-1)[b,:] . Wfc + bfc  (tile rows 0,4,8,12)
    {
        const int row = tid >> 5, l = tid & 31;
        if (row < 16 && (row & 3) == 0) {
            float s = 0.f;
            #pragma unroll
            for (int k = 0; k < 4; ++k)
                s += hfin[row * HFS + l + 32 * k] * Wfc[l + 32 * k];
            #pragma unroll
            for (int d = 16; d >= 1; d >>= 1) s += __shfl_down(s, d, 32);
            if (l == 0) out[brow + (row >> 2)] = s + bfc[0];
        }
    }
}

extern "C" void kernel_launch(void* const* d_in, const int* in_sizes, int n_in,
                              void* d_out, int out_size, void* d_ws, size_t ws_size,
                              hipStream_t stream) {
    const float* x    = (const float*)d_in[0];
    const float* Wih0 = (const float*)d_in[1];
    const float* Whh0 = (const float*)d_in[2];
    const float* bih0 = (const float*)d_in[3];
    const float* bhh0 = (const float*)d_in[4];
    const float* Wih1 = (const float*)d_in[5];
    const float* Whh1 = (const float*)d_in[6];
    const float* bih1 = (const float*)d_in[7];
    const float* bhh1 = (const float*)d_in[8];
    const float* Wfc  = (const float*)d_in[9];
    const float* bfc  = (const float*)d_in[10];
    float* out = (float*)d_out;

    hipLaunchKernelGGL(gru_fused, dim3(512 / BT), dim3(NTHR), 0, stream,
                       x, Wih0, Whh0, bih0, bhh0, Wih1, Whh1, bih1, bhh1, Wfc, bfc, out);
}

// Round 4
// 351.292 us; speedup vs baseline: 1.2468x; 1.1919x over previous
//
#include <hip/hip_runtime.h>
#include <stdint.h>

typedef __bf16 bf16x8 __attribute__((ext_vector_type(8)));
typedef float  floatx4 __attribute__((ext_vector_type(4)));
typedef int    i32x4  __attribute__((ext_vector_type(4)));

#define T_LEN 512
#define NG    (T_LEN / 4)   // 128 time-groups of 4 steps
#define BT    4             // batch rows per block -> 128 blocks
#define NTHR  1024          // 16 waves: 0-7 = layer0 (+x staging), 8-15 = layer1
#define XS    72            // x group-tile row stride (bf16)
#define HIS   144           // h int8 LDS row stride (bytes)
#define HFS   132           // final h1 fp32 row stride

#if __has_builtin(__builtin_amdgcn_exp2f)
#define EXP2(x) __builtin_amdgcn_exp2f(x)
#else
#define EXP2(x) exp2f(x)
#endif

#define MFMA_BF(a,b,c)  __builtin_amdgcn_mfma_f32_16x16x32_bf16((a),(b),(c),0,0,0)
#define MFMA_I8(a,b,c)  __builtin_amdgcn_mfma_i32_16x16x64_i8((a),(b),(c),0,0,0)

// Raw workgroup barrier: drains LDS ops only (lgkmcnt), NOT vmcnt — global
// x-prefetch loads stay in flight across barriers.
#define BARRIER_LDS() asm volatile("s_waitcnt lgkmcnt(0)\n\ts_barrier" ::: "memory")

// quantization: h -> q*1/127 ; w -> q*1/254 (|w| clamped at 0.5)
#define L2E   1.4426950408889634f
#define S_RZ  (-L2E / (254.f * 127.f))        // i32 -> -log2e * preact
#define S_N   (-2.f * L2E / (254.f * 127.f))  // i32 -> -2*log2e * preact

__device__ __forceinline__ float rcpf(float x) { return __builtin_amdgcn_rcpf(x); }

// bf16 B-fragment with folded scale (x-side weights)
__device__ __forceinline__ bf16x8 wfrag_bf(const float* W, int ldk, int row, int k0, float scale) {
    const float* p = W + (size_t)row * ldk + k0;
    bf16x8 r;
    #pragma unroll
    for (int j = 0; j < 8; ++j) r[j] = (__bf16)(p[j] * scale);
    return r;
}
// int8 B-fragment: 16 weights along K, quantized *254, clamped +-127, packed LE
__device__ __forceinline__ i32x4 wfrag_i8(const float* W, int ldk, int row, int k0) {
    const float* p = W + (size_t)row * ldk + k0;
    i32x4 r;
    #pragma unroll
    for (int d = 0; d < 4; ++d) {
        uint32_t dw = 0;
        #pragma unroll
        for (int j = 0; j < 4; ++j) {
            float q = __builtin_rintf(p[d * 4 + j] * 254.f);
            q = fminf(127.f, fmaxf(-127.f, q));
            dw |= ((uint32_t)((int)q & 0xff)) << (8 * j);
        }
        r[d] = (int)dw;
    }
    return r;
}

// TIME-BATCHED version: the feed-forward GEMMs (L0 x-side; L1 input-side on
// h0) are re-tiled so the 16-row MFMA A-tile = 4 timesteps x 4 batch rows
// (row = p + 4*b). ONE set of 6 MFMAs per wave then serves 4 steps; the
// gate lane (quad=b) finds step-p's value in acc[p] (compile-time p via 4x
// unroll). The sequential hidden-side GEMMs are unchanged (b-major rows
// {0,4,8,12}). L1 runs at group lag 4. All re-associations are exact-i32
// or identical fp sequences -> bit-identical output.
// MFMA issue per SIMD per step drops ~967 -> ~610 cy.
__global__ __launch_bounds__(NTHR, 4) void gru_fused(
    const float* __restrict__ x,
    const float* __restrict__ Wih0, const float* __restrict__ Whh0,
    const float* __restrict__ bih0, const float* __restrict__ bhh0,
    const float* __restrict__ Wih1, const float* __restrict__ Whh1,
    const float* __restrict__ bih1, const float* __restrict__ bhh1,
    const float* __restrict__ Wfc,  const float* __restrict__ bfc,
    float* __restrict__ out)
{
    __shared__ __align__(16) __bf16      xg[2][16 * XS];    // x group tile (p+4b rows)
    __shared__ __align__(16) signed char h0b[2][16 * HIS];  // h0 b-major (L0 hidden)
    __shared__ __align__(16) signed char h0g[2][16 * HIS];  // h0 group tile (L1 input)
    __shared__ __align__(16) signed char h1b[2][16 * HIS];  // h1 b-major (L1 hidden)
    __shared__ __align__(16) float       hfin[16 * HFS];

    const int tid  = threadIdx.x;
    const int lane = tid & 63;
    const int ln16 = lane & 15;
    const int quad = lane >> 4;
    const int q8   = quad * 8;        // bf16 k-offset (elements)
    const int q16  = quad * 16;       // int8 k-offset (bytes)
    const int wave = tid >> 6;        // 0..15
    const int brow = blockIdx.x * BT;

    for (int i = tid; i < 16 * HIS; i += NTHR) {
        h0b[0][i] = 0; h0b[1][i] = 0;
        h0g[0][i] = 0; h0g[1][i] = 0;
        h1b[0][i] = 0; h1b[1][i] = 0;
    }
    for (int i = tid; i < 16 * XS; i += NTHR) {
        xg[0][i] = (__bf16)0.f; xg[1][i] = (__bf16)0.f;
    }
    __syncthreads();                  // init barrier

    if (wave < 8) {
        // ===== layer-0: cols [16w,16w+16); x-side bf16 (time-batched), hidden i8 =====
        const int c = wave * 16 + ln16;
        const float bNi = -2.f * L2E * bih0[256 + c];
        const float bNh = -2.f * L2E * bhh0[256 + c];
        const float bR  = -L2E * (bih0[c] + bhh0[c]);
        const float bZ  = -L2E * (bih0[128 + c] + bhh0[128 + c]);
        bf16x8 wI[3][2];              // x-side, scale-folded
        i32x4  wH[3][2];              // hidden int8 K=64
        #pragma unroll
        for (int g = 0; g < 3; ++g) {
            const int row = g * 128 + c;
            const float sc = (g == 2) ? (-2.f * L2E) : (-L2E);
            #pragma unroll
            for (int q = 0; q < 2; ++q) {
                wI[g][q] = wfrag_bf(Wih0, 64, row, q * 32 + q8, sc);
                wH[g][q] = wfrag_i8(Whh0, 128, row, q * 64 + q16);
            }
        }

        // staging: 256 loaders (lanes 0..31 of each L0 wave)
        const bool loader = (lane < 32);
        const int lidx = wave * 32 + lane;
        const int sb = (lidx >> 6) & 3, scg = lidx & 63;
        const float* xp = x + (size_t)(brow + sb) * T_LEN * 64 + scg;
        float vx0 = 0.f, vx1 = 0.f, vx2 = 0.f;
        if (loader) {
            // prologue: x(0..3) -> xg[0] rows tq+4*sb; prefetch x(4..6)
            #pragma unroll
            for (int tq = 0; tq < 4; ++tq)
                xg[0][(tq + 4 * sb) * XS + scg] = (__bf16)xp[(size_t)tq * 64];
            vx0 = xp[4 * 64];
            vx1 = xp[5 * 64];
            vx2 = xp[6 * 64];
        }
        __syncthreads();              // publish xg[0]

        float hfv = 0.f;
        floatx4 pR, pZ, pNi;          // group x-side accs: acc[p] = step 4G+p
        for (int G = 0; G <= NG; ++G) {
            const bool act = (G < NG);
            #pragma unroll
            for (int p = 0; p < 4; ++p) {
                const int tt = 4 * G + p;
                __builtin_amdgcn_sched_barrier(0);
                BARRIER_LDS();        // the ONLY per-step barrier (lgkm only)
                // staging: write x(tt+4) into xg[(G+1)&1] row p+4*sb
                if (loader) {
                    if (tt + 4 < T_LEN)
                        xg[(G + 1) & 1][(p + 4 * sb) * XS + scg] = (__bf16)vx0;
                    vx0 = vx1; vx1 = vx2;
                    int tl = tt + 7; if (tl > T_LEN - 1) tl = T_LEN - 1;
                    vx2 = xp[(size_t)tl * 64];
                }
                if (act) {
                    if (p == 0) {     // group x-side GEMM: steps 4G..4G+3
                        bf16x8 ax0 = *(const bf16x8*)&xg[G & 1][ln16 * XS + q8];
                        bf16x8 ax1 = *(const bf16x8*)&xg[G & 1][ln16 * XS + 32 + q8];
                        floatx4 fR  = {bR, bR, bR, bR};
                        floatx4 fZ  = {bZ, bZ, bZ, bZ};
                        floatx4 fNi = {bNi, bNi, bNi, bNi};
                        fR  = MFMA_BF(ax0, wI[0][0], fR);  fR  = MFMA_BF(ax1, wI[0][1], fR);
                        fZ  = MFMA_BF(ax0, wI[1][0], fZ);  fZ  = MFMA_BF(ax1, wI[1][1], fZ);
                        fNi = MFMA_BF(ax0, wI[2][0], fNi); fNi = MFMA_BF(ax1, wI[2][1], fNi);
                        pR = fR; pZ = fZ; pNi = fNi;
                    }
                    // hidden side of step tt (sequential)
                    const int Rp = (tt + 1) & 1, Wc = tt & 1;
                    i32x4 ah[2];
                    #pragma unroll
                    for (int q = 0; q < 2; ++q)
                        ah[q] = *(const i32x4*)&h0b[Rp][ln16 * HIS + q * 64 + q16];
                    i32x4 cR = {0,0,0,0}, cZ = {0,0,0,0}, cNh = {0,0,0,0};
                    #pragma unroll
                    for (int q = 0; q < 2; ++q) {
                        cR  = MFMA_I8(ah[q], wH[0][q], cR);
                        cZ  = MFMA_I8(ah[q], wH[1][q], cZ);
                        cNh = MFMA_I8(ah[q], wH[2][q], cNh);
                    }
                    // gate math; x-side value for this step = acc reg p
                    const float pr  = fmaf((float)cR[0],  S_RZ, pR[p]);
                    const float pz  = fmaf((float)cZ[0],  S_RZ, pZ[p]);
                    const float phn = fmaf((float)cNh[0], S_N,  bNh);
                    const float r = rcpf(1.f + EXP2(pr));
                    const float z = rcpf(1.f + EXP2(pz));
                    const float n = 2.f * rcpf(1.f + EXP2(fmaf(r, phn, pNi[p]))) - 1.f;
                    const float h = n + z * (hfv - n);
                    hfv = h;
                    const signed char qv = (signed char)(int)__builtin_rintf(h * 127.f);
                    h0b[Wc][(quad * 4) * HIS + c] = qv;          // for L0 hidden (t+1)
                    h0g[G & 1][(p + 4 * quad) * HIS + c] = qv;   // group tile for L1
                }
            }
        }
    } else {
        // ===== layer-1 (group lag 4): cols [16wv,16wv+16); all int8 =====
        const int wv = wave - 8;
        const int c  = wv * 16 + ln16;
        const float bNi1 = -2.f * L2E * bih1[256 + c];
        const float bNh1 = -2.f * L2E * bhh1[256 + c];
        const float bR1  = -L2E * (bih1[c] + bhh1[c]);
        const float bZ1  = -L2E * (bih1[128 + c] + bhh1[128 + c]);
        i32x4 wI[3][2], wH[3][2];
        #pragma unroll
        for (int g = 0; g < 3; ++g) {
            const int row = g * 128 + c;
            #pragma unroll
            for (int q = 0; q < 2; ++q) {
                wI[g][q] = wfrag_i8(Wih1, 128, row, q * 64 + q16);
                wH[g][q] = wfrag_i8(Whh1, 128, row, q * 64 + q16);
            }
        }
        __syncthreads();              // match L0's xg-publish barrier

        float hfv = 0.f;
        i32x4 gR, gZ, gNi;            // group input-side accs: acc[p] = step 4(G-1)+p
        for (int G = 0; G <= NG; ++G) {
            const bool act = (G >= 1);
            #pragma unroll
            for (int p = 0; p < 4; ++p) {
                __builtin_amdgcn_sched_barrier(0);
                BARRIER_LDS();
                if (act) {
                    if (p == 0) {     // group input-side GEMM on h0(4(G-1)..4(G-1)+3)
                        i32x4 ag[2];
                        #pragma unroll
                        for (int q = 0; q < 2; ++q)
                            ag[q] = *(const i32x4*)&h0g[(G - 1) & 1][ln16 * HIS + q * 64 + q16];
                        i32x4 aR = {0,0,0,0}, aZ = {0,0,0,0}, aN = {0,0,0,0};
                        #pragma unroll
                        for (int q = 0; q < 2; ++q) {
                            aR = MFMA_I8(ag[q], wI[0][q], aR);
                            aZ = MFMA_I8(ag[q], wI[1][q], aZ);
                            aN = MFMA_I8(ag[q], wI[2][q], aN);
                        }
                        gR = aR; gZ = aZ; gNi = aN;
                    }
                    // hidden side of L1 step s = 4(G-1)+p (sequential)
                    const int s  = 4 * (G - 1) + p;
                    const int Rp = (s + 1) & 1, Wc = s & 1;
                    i32x4 a1[2];
                    #pragma unroll
                    for (int q = 0; q < 2; ++q)
                        a1[q] = *(const i32x4*)&h1b[Rp][ln16 * HIS + q * 64 + q16];
                    i32x4 cR = {0,0,0,0}, cZ = {0,0,0,0}, cNh = {0,0,0,0};
                    #pragma unroll
                    for (int q = 0; q < 2; ++q) {
                        cR  = MFMA_I8(a1[q], wH[0][q], cR);
                        cZ  = MFMA_I8(a1[q], wH[1][q], cZ);
                        cNh = MFMA_I8(a1[q], wH[2][q], cNh);
                    }
                    // gate math; input-side value = group acc reg p (exact i32 add)
                    const float pr  = fmaf((float)(cR[0] + gR[p]), S_RZ, bR1);
                    const float pz  = fmaf((float)(cZ[0] + gZ[p]), S_RZ, bZ1);
                    const float pin = fmaf((float)gNi[p], S_N, bNi1);
                    const float phn = fmaf((float)cNh[0], S_N, bNh1);
                    const float r = rcpf(1.f + EXP2(pr));
                    const float z = rcpf(1.f + EXP2(pz));
                    const float n = 2.f * rcpf(1.f + EXP2(fmaf(r, phn, pin))) - 1.f;
                    const float h = n + z * (hfv - n);
                    hfv = h;
                    h1b[Wc][(quad * 4) * HIS + c] =
                        (signed char)(int)__builtin_rintf(h * 127.f);
                }
            }
        }
        // publish final h1 (fp32 state) for the FC epilogue
        hfin[(quad * 4) * HFS + c] = hfv;
    }

    __syncthreads();
    // final FC: out[b] = h1(T-1)[b,:] . Wfc + bfc  (tile rows 0,4,8,12)
    {
        const int row = tid >> 5, l = tid & 31;
        if (row < 16 && (row & 3) == 0) {
            float s = 0.f;
            #pragma unroll
            for (int k = 0; k < 4; ++k)
                s += hfin[row * HFS + l + 32 * k] * Wfc[l + 32 * k];
            #pragma unroll
            for (int d = 16; d >= 1; d >>= 1) s += __shfl_down(s, d, 32);
            if (l == 0) out[brow + (row >> 2)] = s + bfc[0];
        }
    }
}

extern "C" void kernel_launch(void* const* d_in, const int* in_sizes, int n_in,
                              void* d_out, int out_size, void* d_ws, size_t ws_size,
                              hipStream_t stream) {
    const float* x    = (const float*)d_in[0];
    const float* Wih0 = (const float*)d_in[1];
    const float* Whh0 = (const float*)d_in[2];
    const float* bih0 = (const float*)d_in[3];
    const float* bhh0 = (const float*)d_in[4];
    const float* Wih1 = (const float*)d_in[5];
    const float* Whh1 = (const float*)d_in[6];
    const float* bih1 = (const float*)d_in[7];
    const float* bhh1 = (const float*)d_in[8];
    const float* Wfc  = (const float*)d_in[9];
    const float* bfc  = (const float*)d_in[10];
    float* out = (float*)d_out;

    hipLaunchKernelGGL(gru_fused, dim3(512 / BT), dim3(NTHR), 0, stream,
                       x, Wih0, Whh0, bih0, bhh0, Wih1, Whh1, bih1, bhh1, Wfc, bfc, out);
}